// Round 5
// baseline (503.359 us; speedup 1.0000x reference)
//
#include <hip/hip_runtime.h>
#include <cstdint>
#include <cstddef>

// Problem constants (B=4, T=2048, C=1024, H=16, S=64)
#define TT 2048
#define CC 1024
#define HH 16
#define SS 64
#define MROWS 8192  // B*T
#define KVRN 3072   // fused k|v|r width
#define NCH 32      // WKV chunks per sequence
#define LCH 64      // steps per chunk (TT/NCH)

using short8 = __attribute__((ext_vector_type(8))) short;
using f32x4  = __attribute__((ext_vector_type(4))) float;

__device__ __forceinline__ float b2f(unsigned short u) {
  union { unsigned int i; float f; } c; c.i = ((unsigned int)u) << 16; return c.f;
}
__device__ __forceinline__ unsigned short f2b(float f) {
  union { float f; unsigned int i; } c; c.f = f;
  unsigned int r = c.i + 0x7fffu + ((c.i >> 16) & 1u);  // RNE; inputs finite
  return (unsigned short)(r >> 16);
}

// async global->LDS, 16 bytes per lane (LDS dst = wave-uniform base + lane*16; global per-lane)
typedef const __attribute__((address_space(1))) unsigned int* gas_ptr;
typedef __attribute__((address_space(3))) unsigned int* las_ptr;
__device__ __forceinline__ void gl_lds16(const unsigned short* g, unsigned short* l) {
  __builtin_amdgcn_global_load_lds((gas_ptr)g, (las_ptr)l, 16, 0, 0);
}

// ---------------- fused: all weights fp32->bf16 + LN1 + x2:=x seed, one launch ----------
// blocks [0,12288): cvt; blocks [12288,20480): LN1 row (blockIdx-12288)
__global__ __launch_bounds__(256) void cvt_ln_kernel(const float* __restrict__ Wk,
                                                     const float* __restrict__ Wv,
                                                     const float* __restrict__ Wr,
                                                     const float* __restrict__ Wo,
                                                     const float* __restrict__ Wffk,
                                                     const float* __restrict__ Wffv,
                                                     unsigned short* __restrict__ dst,
                                                     const float* __restrict__ x,
                                                     const float* __restrict__ g,
                                                     const float* __restrict__ bta,
                                                     unsigned short* __restrict__ xlo,
                                                     float* __restrict__ x2o) {
  const size_t M1 = 1048576;
  const int tid = threadIdx.x;
  if (blockIdx.x < 12288) {
    size_t i = ((size_t)blockIdx.x * 256 + tid) * 4;
    const float* src; size_t off;
    if      (i <  1 * M1) { src = Wk;   off = 0;      }
    else if (i <  2 * M1) { src = Wv;   off = 1 * M1; }
    else if (i <  3 * M1) { src = Wr;   off = 2 * M1; }
    else if (i <  4 * M1) { src = Wo;   off = 3 * M1; }
    else if (i <  8 * M1) { src = Wffk; off = 4 * M1; }
    else                  { src = Wffv; off = 8 * M1; }
    float4 v = *(const float4*)(src + (i - off));
    *(ushort4*)(dst + i) = make_ushort4(f2b(v.x), f2b(v.y), f2b(v.z), f2b(v.w));
    return;
  }
  const int row = blockIdx.x - 12288;
  const float* xr = x + (size_t)row * CC;
  float4 v = *(const float4*)(xr + tid * 4);
  *(float4*)(x2o + (size_t)row * CC + tid * 4) = v;  // seed x2 = x (Wo GEMM atomic-adds)
  float s  = v.x + v.y + v.z + v.w;
  float ss = v.x * v.x + v.y * v.y + v.z * v.z + v.w * v.w;
#pragma unroll
  for (int off = 32; off > 0; off >>= 1) {
    s  += __shfl_xor(s, off, 64);
    ss += __shfl_xor(ss, off, 64);
  }
  __shared__ float ls[4], lss[4];
  if ((tid & 63) == 0) { ls[tid >> 6] = s; lss[tid >> 6] = ss; }
  __syncthreads();
  s  = ls[0] + ls[1] + ls[2] + ls[3];
  ss = lss[0] + lss[1] + lss[2] + lss[3];
  const float mean = s * (1.0f / CC);
  const float var  = ss * (1.0f / CC) - mean * mean;
  const float rstd = rsqrtf(var + 1e-5f);
  float4 gv = *(const float4*)(g + tid * 4);
  float4 bv = *(const float4*)(bta + tid * 4);
  ushort4 o = make_ushort4(f2b((v.x - mean) * rstd * gv.x + bv.x),
                           f2b((v.y - mean) * rstd * gv.y + bv.y),
                           f2b((v.z - mean) * rstd * gv.z + bv.z),
                           f2b((v.w - mean) * rstd * gv.w + bv.w));
  *(ushort4*)(xlo + (size_t)row * CC + tid * 4) = o;
}

// ---------------- LayerNorm (fp32 in, bf16 out) + fp32 passthrough seed ----------------
// outc gets a copy of the fp32 input row (seeds `out` with x2 for the atomic split-K GEMM)
__global__ __launch_bounds__(256) void ln_kernel(const float* __restrict__ x,
                                                 const float* __restrict__ g,
                                                 const float* __restrict__ bta,
                                                 unsigned short* __restrict__ out,
                                                 float* __restrict__ outc) {
  const int row = blockIdx.x;
  const int tid = threadIdx.x;
  const float* xr = x + (size_t)row * CC;
  float4 v = *(const float4*)(xr + tid * 4);
  *(float4*)(outc + (size_t)row * CC + tid * 4) = v;  // seed out = x2
  float s  = v.x + v.y + v.z + v.w;
  float ss = v.x * v.x + v.y * v.y + v.z * v.z + v.w * v.w;
#pragma unroll
  for (int off = 32; off > 0; off >>= 1) {
    s  += __shfl_xor(s, off, 64);
    ss += __shfl_xor(ss, off, 64);
  }
  __shared__ float ls[4], lss[4];
  if ((tid & 63) == 0) { ls[tid >> 6] = s; lss[tid >> 6] = ss; }
  __syncthreads();
  s  = ls[0] + ls[1] + ls[2] + ls[3];
  ss = lss[0] + lss[1] + lss[2] + lss[3];
  const float mean = s * (1.0f / CC);
  const float var  = ss * (1.0f / CC) - mean * mean;
  const float rstd = rsqrtf(var + 1e-5f);
  float4 gv = *(const float4*)(g + tid * 4);
  float4 bv = *(const float4*)(bta + tid * 4);
  ushort4 o = make_ushort4(f2b((v.x - mean) * rstd * gv.x + bv.x),
                           f2b((v.y - mean) * rstd * gv.y + bv.y),
                           f2b((v.z - mean) * rstd * gv.z + bv.z),
                           f2b((v.w - mean) * rstd * gv.w + bv.w));
  *(ushort4*)(out + (size_t)row * CC + tid * 4) = o;
}

// ---------------- WKV hierarchical scan, 2 kernels ----------------
__global__ __launch_bounds__(64) void wkv_local(const unsigned short* __restrict__ kvr,
                                                const float* __restrict__ td,
                                                const float* __restrict__ tfp,
                                                float* __restrict__ scratch) {
  const int blk = blockIdx.x;
  const int bh = blk >> 5, c = blk & (NCH - 1);
  const int b = bh >> 4, h = bh & 15;
  const int s = threadIdx.x;
  const int ch = h * SS + s;
  const float e = __expf(td[ch]);
  const float d = __expf(-e);
  const float tfir = __expf(tfp[ch]);
  size_t idx = ((size_t)b * TT + (size_t)c * LCH) * KVRN + ch;
  float num = 0.f, den = 0.f;
  for (int i = 0; i < LCH; ++i) {
    float w = __expf(fminf(b2f(kvr[idx]), 30.f));
    if (c == 0 && i == 0) w *= tfir;  // time_first seeding at t==0
    float vv = b2f(kvr[idx + 1024]);
    num = d * num + w * vv;
    den = d * den + w;
    idx += KVRN;
  }
  float* o = scratch + ((size_t)bh * NCH + c) * 128;
  o[s] = num; o[64 + s] = den;
}

__global__ __launch_bounds__(64) void wkv_emit(const unsigned short* __restrict__ kvr,
                                               const float* __restrict__ td,
                                               const float* __restrict__ tfp,
                                               const float* __restrict__ scratch,
                                               unsigned short* __restrict__ rwkv) {
  const int blk = blockIdx.x;
  const int bh = blk >> 5, c = blk & (NCH - 1);
  const int b = bh >> 4, h = bh & 15;
  const int s = threadIdx.x;
  const int ch = h * SS + s;
  const float e = __expf(td[ch]);
  const float d = __expf(-e);
  const float Dc = __expf(-e * (float)LCH);
  const float tfir = __expf(tfp[ch]);
  float num = 0.f, den = 0.f;
  const float* sc = scratch + (size_t)bh * NCH * 128;
  for (int cc = 0; cc < c; ++cc) {
    num = Dc * num + sc[cc * 128 + s];
    den = Dc * den + sc[cc * 128 + 64 + s];
  }
  size_t idx = ((size_t)b * TT + (size_t)c * LCH) * KVRN + ch;
  size_t odx = ((size_t)b * TT + (size_t)c * LCH) * CC + ch;
  for (int i = 0; i < LCH; ++i) {
    float w = __expf(fminf(b2f(kvr[idx]), 30.f));
    if (c == 0 && i == 0) w *= tfir;
    float vv = b2f(kvr[idx + 1024]);
    num = d * num + w * vv;
    den = d * den + w;
    float o = num / (den + 1e-6f);
    float rr = b2f(kvr[idx + 2048]);
    float sg = 1.0f / (1.0f + __expf(-rr));
    rwkv[odx] = f2b(sg * o);
    idx += KVRN;
    odx += CC;
  }
}

// ---------------- bf16 MFMA GEMM: C[M,N] = A[M,K] @ Bw[N,K]^T (round-0 original) -------
// 128x128 tile, BK=32, 4 waves of 64x64, XOR-swizzled LDS (0 conflicts), gl_lds staging,
// 3 LDS buffers, prefetch distance 2, raw s_barrier preceded by s_waitcnt vmcnt(4).
// EP=0: bf16 store; EP=1: relu^2 -> bf16; EP=2: fp32 store with residual add
template <int EP>
__global__ __launch_bounds__(256, 3) void gemm_bt(const unsigned short* __restrict__ A,
                                                  const unsigned short* __restrict__ Bw,
                                                  void* __restrict__ outv,
                                                  const float* __restrict__ res,
                                                  int N, int K) {
  __shared__ __align__(16) unsigned short As[3][128 * 32];
  __shared__ __align__(16) unsigned short Bs[3][128 * 32];
  const int tid = threadIdx.x;

  const int nbn = N >> 7;
  const int per_grp = nbn << 4;
  const int bid = blockIdx.x;
  const int grp = bid / per_grp;
  const int rem = bid - grp * per_grp;
  const int bm = (grp << 4) + (rem & 15);
  const int bn = rem >> 4;

  const int ch0 = tid, ch1 = tid + 256;
  const int r0 = ch0 >> 2, q0 = (ch0 & 3) ^ ((ch0 >> 3) & 3);
  const int r1 = ch1 >> 2, q1 = (ch1 & 3) ^ ((ch1 >> 3) & 3);
  const unsigned short* ga0 = A  + (size_t)(bm * 128 + r0) * K + q0 * 8;
  const unsigned short* ga1 = A  + (size_t)(bm * 128 + r1) * K + q1 * 8;
  const unsigned short* gb0 = Bw + (size_t)(bn * 128 + r0) * K + q0 * 8;
  const unsigned short* gb1 = Bw + (size_t)(bn * 128 + r1) * K + q1 * 8;
  const int so0 = ch0 * 8, so1 = ch1 * 8;

  const int lane = tid & 63;
  const int w    = tid >> 6;
  const int q    = lane >> 4, r16 = lane & 15;
  const int qs   = q ^ ((r16 >> 1) & 3);
  const int wrow = (w >> 1) * 64, wcol = (w & 1) * 64;

  f32x4 acc[4][4] = {};

  auto stage = [&](int b3) {
    gl_lds16(ga0, &As[b3][so0]);
    gl_lds16(ga1, &As[b3][so1]);
    gl_lds16(gb0, &Bs[b3][so0]);
    gl_lds16(gb1, &Bs[b3][so1]);
    ga0 += 32; ga1 += 32; gb0 += 32; gb1 += 32;
  };

  const int iters = K >> 5;
  stage(0);
  stage(1);

  int cb = 0, pb = 2;
  for (int i = 0; i < iters; ++i) {
    __builtin_amdgcn_s_waitcnt(0x0F74);
    __builtin_amdgcn_sched_barrier(0);
    asm volatile("s_barrier");
    __builtin_amdgcn_sched_barrier(0);
    if (i + 2 < iters) stage(pb);

    const unsigned short* Ab = &As[cb][0];
    const unsigned short* Bb = &Bs[cb][0];
    short8 af[4], bfr[4];
#pragma unroll
    for (int mi = 0; mi < 4; ++mi)
      af[mi] = *(const short8*)(Ab + ((wrow + mi * 16 + r16) * 4 + qs) * 8);
#pragma unroll
    for (int ni = 0; ni < 4; ++ni)
      bfr[ni] = *(const short8*)(Bb + ((wcol + ni * 16 + r16) * 4 + qs) * 8);
#pragma unroll
    for (int mi = 0; mi < 4; ++mi)
#pragma unroll
      for (int ni = 0; ni < 4; ++ni)
        acc[mi][ni] = __builtin_amdgcn_mfma_f32_16x16x32_bf16(af[mi], bfr[ni], acc[mi][ni], 0, 0, 0);

    cb = (cb == 2) ? 0 : cb + 1;
    pb = (pb == 2) ? 0 : pb + 1;
  }

#pragma unroll
  for (int mi = 0; mi < 4; ++mi) {
#pragma unroll
    for (int r = 0; r < 4; ++r) {
      const int grow = bm * 128 + wrow + mi * 16 + q * 4 + r;
#pragma unroll
      for (int ni = 0; ni < 4; ++ni) {
        const int gcol = bn * 128 + wcol + ni * 16 + r16;
        const size_t idx = (size_t)grow * N + gcol;
        float vv = acc[mi][ni][r];
        if (EP == 2) {
          ((float*)outv)[idx] = res[idx] + vv;
        } else {
          if (EP == 1) { vv = fmaxf(vv, 0.0f); vv = vv * vv; }
          ((unsigned short*)outv)[idx] = f2b(vv);
        }
      }
    }
  }
}

// ---------------- bf16 MFMA GEMM, 256x128 tile, 4 waves of 128x64 -----------------------
// Same schedule/swizzle/MFMA as gemm_bt; wave tile 128x64 cuts LDS-read bytes/FLOP by 25%
// (traffic/FLOP = 2B*(1/Mw+1/Nw)). Per wave K-step: 12 ds_read_b128 -> 32 MFMA.
// Staging: A tile 256x32 (1024 chunks), B tile 128x32 (512 chunks); thread stages 6
// chunks (4 A rows r0+{0,64,128,192}, 2 B rows r0+{0,64}), all same swizzled k-group
// since row+64 preserves (row>>1)&3 parity class used by chunk mapping. vmcnt(6)
// retires exactly the previous tile's 6 chunks (prefetch distance 2, as gemm_bt).
// Fragment reads: identical 16x16 pattern as gemm_bt => identical (zero) bank conflicts.
// EP=1: relu^2 -> bf16; EP=3: fp32 unsafeAtomicAdd (split-K / pre-seeded residual)
template <int EP>
__global__ __launch_bounds__(256, 2) void gemm_wide(const unsigned short* __restrict__ A,
                                                    const unsigned short* __restrict__ Bw,
                                                    void* __restrict__ outv,
                                                    int N, int Kfull, int Kloop) {
  __shared__ __align__(16) unsigned short As[3][256 * 32];
  __shared__ __align__(16) unsigned short Bs[3][128 * 32];
  const int tid = threadIdx.x;

  // grid decode: groups of 16 bm-tiles sweep all bn for L2 reuse of B panels
  const int nbn = N >> 7;
  const int per_grp = nbn << 4;
  const int bid = blockIdx.x;
  const int grp = bid / per_grp;
  const int rem = bid - grp * per_grp;
  const int bm = (grp << 4) + (rem & 15);   // 256-row tile index
  const int bn = rem >> 4;                  // 128-col tile index
  const int koffb = blockIdx.y * Kloop;     // split-K slice offset
  const int iters = Kloop >> 5;

  // staging addresses (chunk c: row=c>>2, slot=c&3, src kgroup=(c&3)^((c>>3)&3);
  // c = tid + 256m keeps the kgroup of tid since 256m contributes 0 mod 4 to c>>3&3... 
  // (tid+256m)>>3 = (tid>>3) + 32m, &3 unchanged)
  const int r0  = tid >> 2;
  const int qsl = ((tid & 3) ^ ((tid >> 3) & 3)) << 3;
  const unsigned short* gA[4];
  const unsigned short* gB[2];
#pragma unroll
  for (int m = 0; m < 4; ++m)
    gA[m] = A + (size_t)(bm * 256 + r0 + 64 * m) * Kfull + koffb + qsl;
#pragma unroll
  for (int m = 0; m < 2; ++m)
    gB[m] = Bw + (size_t)(bn * 128 + r0 + 64 * m) * Kfull + koffb + qsl;
  const int so = tid * 8;

  auto stage = [&](int b3) {
    unsigned short* da = &As[b3][0];
    unsigned short* db = &Bs[b3][0];
#pragma unroll
    for (int m = 0; m < 4; ++m) { gl_lds16(gA[m], da + so + 2048 * m); gA[m] += 32; }
#pragma unroll
    for (int m = 0; m < 2; ++m) { gl_lds16(gB[m], db + so + 2048 * m); gB[m] += 32; }
  };

  const int lane = tid & 63;
  const int w    = tid >> 6;
  const int q    = lane >> 4, r16 = lane & 15;
  const int qs   = q ^ ((r16 >> 1) & 3);
  const int wrow = (w >> 1) * 128, wcol = (w & 1) * 64;  // 2M x 2N waves, 128x64 each

  f32x4 acc[8][4] = {};

  stage(0);
  stage(1);

  int cb = 0, pb = 2;
  for (int i = 0; i < iters; ++i) {
    // retire previous tile's 6 chunks; 6 newer stay in flight (2 phases of margin,
    // same empirical discipline as gemm_bt). imm 0x0F76: vmcnt=6, exp/lgkm = no wait.
    __builtin_amdgcn_s_waitcnt(0x0F76);
    __builtin_amdgcn_sched_barrier(0);
    asm volatile("s_barrier");
    __builtin_amdgcn_sched_barrier(0);
    if (i + 2 < iters) stage(pb);

    const unsigned short* Ab = &As[cb][0];
    const unsigned short* Bb = &Bs[cb][0];
    short8 af[8], bfr[4];
#pragma unroll
    for (int mi = 0; mi < 8; ++mi)
      af[mi] = *(const short8*)(Ab + ((wrow + mi * 16 + r16) * 4 + qs) * 8);
#pragma unroll
    for (int ni = 0; ni < 4; ++ni)
      bfr[ni] = *(const short8*)(Bb + ((wcol + ni * 16 + r16) * 4 + qs) * 8);
#pragma unroll
    for (int mi = 0; mi < 8; ++mi)
#pragma unroll
      for (int ni = 0; ni < 4; ++ni)
        acc[mi][ni] = __builtin_amdgcn_mfma_f32_16x16x32_bf16(af[mi], bfr[ni], acc[mi][ni], 0, 0, 0);

    cb = (cb == 2) ? 0 : cb + 1;
    pb = (pb == 2) ? 0 : pb + 1;
  }

#pragma unroll
  for (int mi = 0; mi < 8; ++mi) {
#pragma unroll
    for (int r = 0; r < 4; ++r) {
      const int grow = bm * 256 + wrow + mi * 16 + q * 4 + r;
#pragma unroll
      for (int ni = 0; ni < 4; ++ni) {
        const int gcol = bn * 128 + wcol + ni * 16 + r16;
        const size_t idx = (size_t)grow * N + gcol;
        float vv = acc[mi][ni][r];
        if (EP == 3) {
          unsafeAtomicAdd((float*)outv + idx, vv);
        } else {
          if (EP == 1) { vv = fmaxf(vv, 0.0f); vv = vv * vv; }
          ((unsigned short*)outv)[idx] = f2b(vv);
        }
      }
    }
  }
}

extern "C" void kernel_launch(void* const* d_in, const int* in_sizes, int n_in,
                              void* d_out, int out_size, void* d_ws, size_t ws_size,
                              hipStream_t stream) {
  const float* x    = (const float*)d_in[0];
  const float* td   = (const float*)d_in[1];
  const float* tf   = (const float*)d_in[2];
  const float* Wk   = (const float*)d_in[3];
  const float* Wv   = (const float*)d_in[4];
  const float* Wr   = (const float*)d_in[5];
  const float* Wo   = (const float*)d_in[6];
  const float* Wffk = (const float*)d_in[7];
  const float* Wffv = (const float*)d_in[8];
  const float* g1   = (const float*)d_in[9];
  const float* b1   = (const float*)d_in[10];
  const float* g2   = (const float*)d_in[11];
  const float* b2   = (const float*)d_in[12];
  float* out = (float*)d_out;

  char* ws = (char*)d_ws;
  const size_t MB = 1024ull * 1024ull;
  unsigned short* WB    = (unsigned short*)ws;              // 24 MB contiguous bf16 weights
  unsigned short* WkvrB = WB;                               // [3072,1024]
  unsigned short* WoB   = WB + 3 * 1048576;                 // [1024,1024]
  unsigned short* WfkB  = WB + 4 * 1048576;                 // [4096,1024]
  unsigned short* WfvB  = WB + 8 * 1048576;                 // [1024,4096]
  unsigned short* xl    = (unsigned short*)(ws + 24 * MB);  // 16 MB (reused as rwkv)
  unsigned short* kvr   = (unsigned short*)(ws + 40 * MB);  // 48 MB [8192,3072] (reused as xl2)
  float*          x2    = (float*)(ws + 88 * MB);           // 32 MB
  unsigned short* hb    = (unsigned short*)(ws + 120 * MB); // 64 MB
  float*          wkvS  = (float*)(ws + 184 * MB);          // 1 MB scan scratch -> total 185 MB
  unsigned short* rwkv  = xl;   // xl dead after kvr GEMM
  unsigned short* xl2   = kvr;  // kvr dead after wkv_emit

  // weights -> bf16 + LN1 + x2:=x seed, fused single launch
  cvt_ln_kernel<<<12288 + MROWS, 256, 0, stream>>>(Wk, Wv, Wr, Wo, Wffk, Wffv, WB,
                                                   x, g1, b1, xl, x2);

  // fused k|v|r GEMM: kvr[M,3072] = xl @ WkvrB^T   (1536 blocks, 3/CU packed)
  gemm_bt<0><<<(KVRN / 128) * (MROWS / 128), 256, 0, stream>>>(xl, WkvrB, kvr, nullptr, KVRN, 1024);

  // WKV hierarchical scan + sigmoid(r) fuse
  wkv_local<<<64 * NCH, 64, 0, stream>>>(kvr, td, tf, wkvS);
  wkv_emit<<<64 * NCH, 64, 0, stream>>>(kvr, td, tf, wkvS, rwkv);

  // x2 += rwkv @ Wo^T  (x2 pre-seeded with x; split-K x2 -> 512 blocks = 2/CU packed)
  gemm_wide<3><<<dim3((MROWS / 256) * (CC / 128), 2), 256, 0, stream>>>(
      rwkv, WoB, x2, CC, 1024, 512);

  // LN2 (+ seed out = x2 for the atomic split-K epilogue below)
  ln_kernel<<<MROWS, 256, 0, stream>>>(x2, g2, b2, xl2, out);

  // h = relu(xl2 @ Wffk^T)^2   (1024 blocks = 4/CU, 2 packed rounds)
  gemm_wide<1><<<dim3((MROWS / 256) * (4096 / 128), 1), 256, 0, stream>>>(
      xl2, WfkB, hb, 4096, 1024, 1024);

  // out += h @ Wffv^T   (split-K x2: 2x256 blocks = 2/CU packed, K=2048 each)
  gemm_wide<3><<<dim3((MROWS / 256) * (CC / 128), 2), 256, 0, stream>>>(
      hb, WfvB, out, CC, 4096, 2048);
}

// Round 6
// 457.123 us; speedup vs baseline: 1.1011x; 1.1011x over previous
//
#include <hip/hip_runtime.h>
#include <cstdint>
#include <cstddef>

// Problem constants (B=4, T=2048, C=1024, H=16, S=64)
#define TT 2048
#define CC 1024
#define HH 16
#define SS 64
#define MROWS 8192  // B*T
#define KVRN 3072   // fused k|v|r width
#define NCH 32      // WKV chunks per sequence
#define LCH 64      // steps per chunk (TT/NCH)

using short8 = __attribute__((ext_vector_type(8))) short;
using f32x4  = __attribute__((ext_vector_type(4))) float;

__device__ __forceinline__ float b2f(unsigned short u) {
  union { unsigned int i; float f; } c; c.i = ((unsigned int)u) << 16; return c.f;
}
__device__ __forceinline__ unsigned short f2b(float f) {
  union { float f; unsigned int i; } c; c.f = f;
  unsigned int r = c.i + 0x7fffu + ((c.i >> 16) & 1u);  // RNE; inputs finite
  return (unsigned short)(r >> 16);
}

// async global->LDS, 16 bytes per lane (LDS dst = wave-uniform base + lane*16; global per-lane)
typedef const __attribute__((address_space(1))) unsigned int* gas_ptr;
typedef __attribute__((address_space(3))) unsigned int* las_ptr;
__device__ __forceinline__ void gl_lds16(const unsigned short* g, unsigned short* l) {
  __builtin_amdgcn_global_load_lds((gas_ptr)g, (las_ptr)l, 16, 0, 0);
}

// ---------------- fused: all weights fp32->bf16 + LN1, one launch ----------------
// blocks [0,12288): cvt; blocks [12288,20480): LN1 row (blockIdx-12288)
__global__ __launch_bounds__(256) void cvt_ln_kernel(const float* __restrict__ Wk,
                                                     const float* __restrict__ Wv,
                                                     const float* __restrict__ Wr,
                                                     const float* __restrict__ Wo,
                                                     const float* __restrict__ Wffk,
                                                     const float* __restrict__ Wffv,
                                                     unsigned short* __restrict__ dst,
                                                     const float* __restrict__ x,
                                                     const float* __restrict__ g,
                                                     const float* __restrict__ bta,
                                                     unsigned short* __restrict__ xlo) {
  const size_t M1 = 1048576;
  const int tid = threadIdx.x;
  if (blockIdx.x < 12288) {
    size_t i = ((size_t)blockIdx.x * 256 + tid) * 4;
    const float* src; size_t off;
    if      (i <  1 * M1) { src = Wk;   off = 0;      }
    else if (i <  2 * M1) { src = Wv;   off = 1 * M1; }
    else if (i <  3 * M1) { src = Wr;   off = 2 * M1; }
    else if (i <  4 * M1) { src = Wo;   off = 3 * M1; }
    else if (i <  8 * M1) { src = Wffk; off = 4 * M1; }
    else                  { src = Wffv; off = 8 * M1; }
    float4 v = *(const float4*)(src + (i - off));
    *(ushort4*)(dst + i) = make_ushort4(f2b(v.x), f2b(v.y), f2b(v.z), f2b(v.w));
    return;
  }
  const int row = blockIdx.x - 12288;
  const float* xr = x + (size_t)row * CC;
  float4 v = *(const float4*)(xr + tid * 4);
  float s  = v.x + v.y + v.z + v.w;
  float ss = v.x * v.x + v.y * v.y + v.z * v.z + v.w * v.w;
#pragma unroll
  for (int off = 32; off > 0; off >>= 1) {
    s  += __shfl_xor(s, off, 64);
    ss += __shfl_xor(ss, off, 64);
  }
  __shared__ float ls[4], lss[4];
  if ((tid & 63) == 0) { ls[tid >> 6] = s; lss[tid >> 6] = ss; }
  __syncthreads();
  s  = ls[0] + ls[1] + ls[2] + ls[3];
  ss = lss[0] + lss[1] + lss[2] + lss[3];
  const float mean = s * (1.0f / CC);
  const float var  = ss * (1.0f / CC) - mean * mean;
  const float rstd = rsqrtf(var + 1e-5f);
  float4 gv = *(const float4*)(g + tid * 4);
  float4 bv = *(const float4*)(bta + tid * 4);
  ushort4 o = make_ushort4(f2b((v.x - mean) * rstd * gv.x + bv.x),
                           f2b((v.y - mean) * rstd * gv.y + bv.y),
                           f2b((v.z - mean) * rstd * gv.z + bv.z),
                           f2b((v.w - mean) * rstd * gv.w + bv.w));
  *(ushort4*)(xlo + (size_t)row * CC + tid * 4) = o;
}

// ---------------- LayerNorm (fp32 in, bf16 out) + fp32 passthrough seed ----------------
// outc gets a copy of the fp32 input row (seeds `out` with x2 for the atomic split-K GEMM)
__global__ __launch_bounds__(256) void ln_kernel(const float* __restrict__ x,
                                                 const float* __restrict__ g,
                                                 const float* __restrict__ bta,
                                                 unsigned short* __restrict__ out,
                                                 float* __restrict__ outc) {
  const int row = blockIdx.x;
  const int tid = threadIdx.x;
  const float* xr = x + (size_t)row * CC;
  float4 v = *(const float4*)(xr + tid * 4);
  *(float4*)(outc + (size_t)row * CC + tid * 4) = v;  // seed out = x2
  float s  = v.x + v.y + v.z + v.w;
  float ss = v.x * v.x + v.y * v.y + v.z * v.z + v.w * v.w;
#pragma unroll
  for (int off = 32; off > 0; off >>= 1) {
    s  += __shfl_xor(s, off, 64);
    ss += __shfl_xor(ss, off, 64);
  }
  __shared__ float ls[4], lss[4];
  if ((tid & 63) == 0) { ls[tid >> 6] = s; lss[tid >> 6] = ss; }
  __syncthreads();
  s  = ls[0] + ls[1] + ls[2] + ls[3];
  ss = lss[0] + lss[1] + lss[2] + lss[3];
  const float mean = s * (1.0f / CC);
  const float var  = ss * (1.0f / CC) - mean * mean;
  const float rstd = rsqrtf(var + 1e-5f);
  float4 gv = *(const float4*)(g + tid * 4);
  float4 bv = *(const float4*)(bta + tid * 4);
  ushort4 o = make_ushort4(f2b((v.x - mean) * rstd * gv.x + bv.x),
                           f2b((v.y - mean) * rstd * gv.y + bv.y),
                           f2b((v.z - mean) * rstd * gv.z + bv.z),
                           f2b((v.w - mean) * rstd * gv.w + bv.w));
  *(ushort4*)(out + (size_t)row * CC + tid * 4) = o;
}

// ---------------- WKV hierarchical scan, 2 kernels ----------------
__global__ __launch_bounds__(64) void wkv_local(const unsigned short* __restrict__ kvr,
                                                const float* __restrict__ td,
                                                const float* __restrict__ tfp,
                                                float* __restrict__ scratch) {
  const int blk = blockIdx.x;
  const int bh = blk >> 5, c = blk & (NCH - 1);
  const int b = bh >> 4, h = bh & 15;
  const int s = threadIdx.x;
  const int ch = h * SS + s;
  const float e = __expf(td[ch]);
  const float d = __expf(-e);
  const float tfir = __expf(tfp[ch]);
  size_t idx = ((size_t)b * TT + (size_t)c * LCH) * KVRN + ch;
  float num = 0.f, den = 0.f;
  for (int i = 0; i < LCH; ++i) {
    float w = __expf(fminf(b2f(kvr[idx]), 30.f));
    if (c == 0 && i == 0) w *= tfir;  // time_first seeding at t==0
    float vv = b2f(kvr[idx + 1024]);
    num = d * num + w * vv;
    den = d * den + w;
    idx += KVRN;
  }
  float* o = scratch + ((size_t)bh * NCH + c) * 128;
  o[s] = num; o[64 + s] = den;
}

__global__ __launch_bounds__(64) void wkv_emit(const unsigned short* __restrict__ kvr,
                                               const float* __restrict__ td,
                                               const float* __restrict__ tfp,
                                               const float* __restrict__ scratch,
                                               unsigned short* __restrict__ rwkv) {
  const int blk = blockIdx.x;
  const int bh = blk >> 5, c = blk & (NCH - 1);
  const int b = bh >> 4, h = bh & 15;
  const int s = threadIdx.x;
  const int ch = h * SS + s;
  const float e = __expf(td[ch]);
  const float d = __expf(-e);
  const float Dc = __expf(-e * (float)LCH);
  const float tfir = __expf(tfp[ch]);
  float num = 0.f, den = 0.f;
  const float* sc = scratch + (size_t)bh * NCH * 128;
  for (int cc = 0; cc < c; ++cc) {
    num = Dc * num + sc[cc * 128 + s];
    den = Dc * den + sc[cc * 128 + 64 + s];
  }
  size_t idx = ((size_t)b * TT + (size_t)c * LCH) * KVRN + ch;
  size_t odx = ((size_t)b * TT + (size_t)c * LCH) * CC + ch;
  for (int i = 0; i < LCH; ++i) {
    float w = __expf(fminf(b2f(kvr[idx]), 30.f));
    if (c == 0 && i == 0) w *= tfir;
    float vv = b2f(kvr[idx + 1024]);
    num = d * num + w * vv;
    den = d * den + w;
    float o = num / (den + 1e-6f);
    float rr = b2f(kvr[idx + 2048]);
    float sg = 1.0f / (1.0f + __expf(-rr));
    rwkv[odx] = f2b(sg * o);
    idx += KVRN;
    odx += CC;
  }
}

// ---------------- bf16 MFMA GEMM: C[M,N] = A[M,K] @ Bw[N,K]^T (round-0 original) -------
// 128x128 tile, BK=32, 4 waves of 64x64, XOR-swizzled LDS (0 conflicts), gl_lds staging,
// 3 LDS buffers, prefetch distance 2, raw s_barrier preceded by s_waitcnt vmcnt(4).
// EP=0: bf16 store; EP=1: relu^2 -> bf16; EP=2: fp32 store with residual add
template <int EP>
__global__ __launch_bounds__(256, 3) void gemm_bt(const unsigned short* __restrict__ A,
                                                  const unsigned short* __restrict__ Bw,
                                                  void* __restrict__ outv,
                                                  const float* __restrict__ res,
                                                  int N, int K) {
  __shared__ __align__(16) unsigned short As[3][128 * 32];
  __shared__ __align__(16) unsigned short Bs[3][128 * 32];
  const int tid = threadIdx.x;

  const int nbn = N >> 7;
  const int per_grp = nbn << 4;
  const int bid = blockIdx.x;
  const int grp = bid / per_grp;
  const int rem = bid - grp * per_grp;
  const int bm = (grp << 4) + (rem & 15);
  const int bn = rem >> 4;

  const int ch0 = tid, ch1 = tid + 256;
  const int r0 = ch0 >> 2, q0 = (ch0 & 3) ^ ((ch0 >> 3) & 3);
  const int r1 = ch1 >> 2, q1 = (ch1 & 3) ^ ((ch1 >> 3) & 3);
  const unsigned short* ga0 = A  + (size_t)(bm * 128 + r0) * K + q0 * 8;
  const unsigned short* ga1 = A  + (size_t)(bm * 128 + r1) * K + q1 * 8;
  const unsigned short* gb0 = Bw + (size_t)(bn * 128 + r0) * K + q0 * 8;
  const unsigned short* gb1 = Bw + (size_t)(bn * 128 + r1) * K + q1 * 8;
  const int so0 = ch0 * 8, so1 = ch1 * 8;

  const int lane = tid & 63;
  const int w    = tid >> 6;
  const int q    = lane >> 4, r16 = lane & 15;
  const int qs   = q ^ ((r16 >> 1) & 3);
  const int wrow = (w >> 1) * 64, wcol = (w & 1) * 64;

  f32x4 acc[4][4] = {};

  auto stage = [&](int b3) {
    gl_lds16(ga0, &As[b3][so0]);
    gl_lds16(ga1, &As[b3][so1]);
    gl_lds16(gb0, &Bs[b3][so0]);
    gl_lds16(gb1, &Bs[b3][so1]);
    ga0 += 32; ga1 += 32; gb0 += 32; gb1 += 32;
  };

  const int iters = K >> 5;
  stage(0);
  stage(1);

  int cb = 0, pb = 2;
  for (int i = 0; i < iters; ++i) {
    __builtin_amdgcn_s_waitcnt(0x0F74);
    __builtin_amdgcn_sched_barrier(0);
    asm volatile("s_barrier");
    __builtin_amdgcn_sched_barrier(0);
    if (i + 2 < iters) stage(pb);

    const unsigned short* Ab = &As[cb][0];
    const unsigned short* Bb = &Bs[cb][0];
    short8 af[4], bfr[4];
#pragma unroll
    for (int mi = 0; mi < 4; ++mi)
      af[mi] = *(const short8*)(Ab + ((wrow + mi * 16 + r16) * 4 + qs) * 8);
#pragma unroll
    for (int ni = 0; ni < 4; ++ni)
      bfr[ni] = *(const short8*)(Bb + ((wcol + ni * 16 + r16) * 4 + qs) * 8);
#pragma unroll
    for (int mi = 0; mi < 4; ++mi)
#pragma unroll
      for (int ni = 0; ni < 4; ++ni)
        acc[mi][ni] = __builtin_amdgcn_mfma_f32_16x16x32_bf16(af[mi], bfr[ni], acc[mi][ni], 0, 0, 0);

    cb = (cb == 2) ? 0 : cb + 1;
    pb = (pb == 2) ? 0 : pb + 1;
  }

#pragma unroll
  for (int mi = 0; mi < 4; ++mi) {
#pragma unroll
    for (int r = 0; r < 4; ++r) {
      const int grow = bm * 128 + wrow + mi * 16 + q * 4 + r;
#pragma unroll
      for (int ni = 0; ni < 4; ++ni) {
        const int gcol = bn * 128 + wcol + ni * 16 + r16;
        const size_t idx = (size_t)grow * N + gcol;
        float vv = acc[mi][ni][r];
        if (EP == 2) {
          ((float*)outv)[idx] = res[idx] + vv;
        } else {
          if (EP == 1) { vv = fmaxf(vv, 0.0f); vv = vv * vv; }
          ((unsigned short*)outv)[idx] = f2b(vv);
        }
      }
    }
  }
}

// ---------------- bf16 MFMA GEMM, 256x128 tile, 512 threads (8 waves of 64x64) ----------
// Identical per-wave structure to gemm_bt (64x64 wave tile, same fragment addressing,
// same swizzle, same 3-buffer distance-2 vmcnt-counted schedule). The ONLY change vs
// gemm_bt: 8 waves/block (4M x 2N of 64x64) -> LDS 72KB -> 2 blocks/CU -> 16 waves/CU
// resident (vs 12), testing the occupancy/latency-hiding hypothesis from rounds 0-5.
// Staging: A tile 256x32 (1024 chunks of 16B), B tile 128x32 (512 chunks); thread t
// stages A chunks t, t+512 and B chunk t. (t+512)>>3 = (t>>3)+64 keeps &3 -> same
// swizzled source k-group as chunk t (round-0-verified mapping). 3 gl_lds/thread/stage;
// ledger: prologue 6 in flight; per iter: vmcnt(3) retires tile i's 3, barrier, stage ->6.
// EP=1: relu^2 -> bf16; EP=3: fp32 unsafeAtomicAdd (split-K, out pre-seeded)
template <int EP>
__global__ __launch_bounds__(512, 2) void gemm512(const unsigned short* __restrict__ A,
                                                  const unsigned short* __restrict__ Bw,
                                                  void* __restrict__ outv,
                                                  int N, int Kfull, int Kloop) {
  __shared__ __align__(16) unsigned short As[3][256 * 32];
  __shared__ __align__(16) unsigned short Bs[3][128 * 32];
  const int tid = threadIdx.x;

  // grid decode: groups of 16 bm-tiles sweep all bn for L2 reuse of B panels
  const int nbn = N >> 7;
  const int per_grp = nbn << 4;
  const int bid = blockIdx.x;
  const int grp = bid / per_grp;
  const int rem = bid - grp * per_grp;
  const int bm = (grp << 4) + (rem & 15);   // 256-row tile index
  const int bn = rem >> 4;                  // 128-col tile index
  const int koffb = blockIdx.y * Kloop;     // split-K slice offset
  const int iters = Kloop >> 5;

  // chunk c: row=c>>2, slot=c&3, source kgroup=(c&3)^((c>>3)&3)
  const int r0  = tid >> 2;                 // A rows 0..127 (chunk t), +128 (chunk t+512)
  const int qsl = ((tid & 3) ^ ((tid >> 3) & 3)) << 3;
  const unsigned short* gA0 = A  + (size_t)(bm * 256 + r0) * Kfull + koffb + qsl;
  const unsigned short* gA1 = gA0 + (size_t)128 * Kfull;
  const unsigned short* gB0 = Bw + (size_t)(bn * 128 + r0) * Kfull + koffb + qsl;
  const int so = tid * 8;

  auto stage = [&](int b3) {
    unsigned short* da = &As[b3][0];
    unsigned short* db = &Bs[b3][0];
    gl_lds16(gA0, da + so);
    gl_lds16(gA1, da + so + 4096);
    gl_lds16(gB0, db + so);
    gA0 += 32; gA1 += 32; gB0 += 32;
  };

  const int lane = tid & 63;
  const int w    = tid >> 6;                // 0..7
  const int q    = lane >> 4, r16 = lane & 15;
  const int qs   = q ^ ((r16 >> 1) & 3);
  const int wrow = (w >> 1) * 64, wcol = (w & 1) * 64;  // 4M x 2N waves, 64x64 each

  f32x4 acc[4][4] = {};

  stage(0);
  stage(1);

  int cb = 0, pb = 2;
  for (int i = 0; i < iters; ++i) {
    // retire tile i's 3 chunks (own); tile i+1's 3 stay in flight. 0x0F73: vmcnt=3.
    __builtin_amdgcn_s_waitcnt(0x0F73);
    __builtin_amdgcn_sched_barrier(0);
    asm volatile("s_barrier");
    __builtin_amdgcn_sched_barrier(0);
    if (i + 2 < iters) stage(pb);

    const unsigned short* Ab = &As[cb][0];
    const unsigned short* Bb = &Bs[cb][0];
    short8 af[4], bfr[4];
#pragma unroll
    for (int mi = 0; mi < 4; ++mi)
      af[mi] = *(const short8*)(Ab + ((wrow + mi * 16 + r16) * 4 + qs) * 8);
#pragma unroll
    for (int ni = 0; ni < 4; ++ni)
      bfr[ni] = *(const short8*)(Bb + ((wcol + ni * 16 + r16) * 4 + qs) * 8);
#pragma unroll
    for (int mi = 0; mi < 4; ++mi)
#pragma unroll
      for (int ni = 0; ni < 4; ++ni)
        acc[mi][ni] = __builtin_amdgcn_mfma_f32_16x16x32_bf16(af[mi], bfr[ni], acc[mi][ni], 0, 0, 0);

    cb = (cb == 2) ? 0 : cb + 1;
    pb = (pb == 2) ? 0 : pb + 1;
  }

#pragma unroll
  for (int mi = 0; mi < 4; ++mi) {
#pragma unroll
    for (int r = 0; r < 4; ++r) {
      const int grow = bm * 256 + wrow + mi * 16 + q * 4 + r;
#pragma unroll
      for (int ni = 0; ni < 4; ++ni) {
        const int gcol = bn * 128 + wcol + ni * 16 + r16;
        const size_t idx = (size_t)grow * N + gcol;
        float vv = acc[mi][ni][r];
        if (EP == 3) {
          unsafeAtomicAdd((float*)outv + idx, vv);
        } else {
          if (EP == 1) { vv = fmaxf(vv, 0.0f); vv = vv * vv; }
          ((unsigned short*)outv)[idx] = f2b(vv);
        }
      }
    }
  }
}

extern "C" void kernel_launch(void* const* d_in, const int* in_sizes, int n_in,
                              void* d_out, int out_size, void* d_ws, size_t ws_size,
                              hipStream_t stream) {
  const float* x    = (const float*)d_in[0];
  const float* td   = (const float*)d_in[1];
  const float* tf   = (const float*)d_in[2];
  const float* Wk   = (const float*)d_in[3];
  const float* Wv   = (const float*)d_in[4];
  const float* Wr   = (const float*)d_in[5];
  const float* Wo   = (const float*)d_in[6];
  const float* Wffk = (const float*)d_in[7];
  const float* Wffv = (const float*)d_in[8];
  const float* g1   = (const float*)d_in[9];
  const float* b1   = (const float*)d_in[10];
  const float* g2   = (const float*)d_in[11];
  const float* b2   = (const float*)d_in[12];
  float* out = (float*)d_out;

  char* ws = (char*)d_ws;
  const size_t MB = 1024ull * 1024ull;
  unsigned short* WB    = (unsigned short*)ws;              // 24 MB contiguous bf16 weights
  unsigned short* WkvrB = WB;                               // [3072,1024]
  unsigned short* WoB   = WB + 3 * 1048576;                 // [1024,1024]
  unsigned short* WfkB  = WB + 4 * 1048576;                 // [4096,1024]
  unsigned short* WfvB  = WB + 8 * 1048576;                 // [1024,4096]
  unsigned short* xl    = (unsigned short*)(ws + 24 * MB);  // 16 MB (reused as rwkv)
  unsigned short* kvr   = (unsigned short*)(ws + 40 * MB);  // 48 MB [8192,3072] (reused as xl2)
  float*          x2    = (float*)(ws + 88 * MB);           // 32 MB
  unsigned short* hb    = (unsigned short*)(ws + 120 * MB); // 64 MB
  float*          wkvS  = (float*)(ws + 184 * MB);          // 1 MB scan scratch -> total 185 MB
  unsigned short* rwkv  = xl;   // xl dead after kvr GEMM
  unsigned short* xl2   = kvr;  // kvr dead after wkv_emit

  // weights -> bf16 + LN1, fused single launch
  cvt_ln_kernel<<<12288 + MROWS, 256, 0, stream>>>(Wk, Wv, Wr, Wo, Wffk, Wffv, WB,
                                                   x, g1, b1, xl);

  // fused k|v|r GEMM: kvr[M,3072] = xl @ WkvrB^T   (1536 blocks, round-0 exact)
  gemm_bt<0><<<(KVRN / 128) * (MROWS / 128), 256, 0, stream>>>(xl, WkvrB, kvr, nullptr, KVRN, 1024);

  // WKV hierarchical scan + sigmoid(r) fuse
  wkv_local<<<64 * NCH, 64, 0, stream>>>(kvr, td, tf, wkvS);
  wkv_emit<<<64 * NCH, 64, 0, stream>>>(kvr, td, tf, wkvS, rwkv);

  // x2 = x + rwkv @ Wo^T   (512 blocks, round-0 exact, deterministic residual)
  gemm_bt<2><<<(CC / 128) * (MROWS / 128), 256, 0, stream>>>(rwkv, WoB, x2, x, 1024, 1024);

  // LN2 (+ seed out = x2 for the atomic split-K Wffv below)
  ln_kernel<<<MROWS, 256, 0, stream>>>(x2, g2, b2, xl2, out);

  // h = relu(xl2 @ Wffk^T)^2   (1024 blocks = 2 resident/CU, 16 waves/CU)
  gemm512<1><<<dim3((MROWS / 256) * (4096 / 128), 1), 512, 0, stream>>>(
      xl2, WfkB, hb, 4096, 1024, 1024);

  // out += h @ Wffv^T   (split-K x2: 2x256 blocks, K=2048 each, fp32 atomic add)
  gemm512<3><<<dim3((MROWS / 256) * (CC / 128), 2), 512, 0, stream>>>(
      hb, WfvB, out, CC, 4096, 2048);
}